// Round 1
// baseline (702.938 us; speedup 1.0000x reference)
//
#include <hip/hip_runtime.h>
#include <cstddef>

constexpr int kDIn  = 1024;
constexpr int kDOut = 1024;
constexpr int kBatch = 32;
constexpr int kE = kDOut + 2 * kDIn + 4;   // 3076
constexpr int kKQRows = 2 * kDIn + 4;      // 2052 rows, starting at e = kDOut

__device__ __forceinline__ float dot4(float4 a, float4 b) {
    return a.x * b.x + a.y * b.y + a.z * b.z + a.w * b.w;
}

__device__ __forceinline__ float waveReduceSum(float v) {
#pragma unroll
    for (int off = 32; off; off >>= 1) v += __shfl_xor(v, off, 64);
    return v;
}

// ---------------------------------------------------------------------------
// Kernel 1: out[b][e] = w[b,e,:] . x[b,:]   for e in [kDOut, kE)
// One wave per row; lane reads float4 at (it*64 + lane) -> fully coalesced.
// ---------------------------------------------------------------------------
__global__ __launch_bounds__(256) void k_matvec_kq(const float* __restrict__ w,
                                                   const float* __restrict__ x,
                                                   float* __restrict__ outv) {
    const int gw   = (blockIdx.x * 256 + threadIdx.x) >> 6;  // global wave id
    const int lane = threadIdx.x & 63;
    const int b = gw / kKQRows;
    const int e = kDOut + (gw % kKQRows);

    const float4* __restrict__ wr = (const float4*)(w + ((size_t)b * kE + e) * kDIn);
    const float4* __restrict__ xr = (const float4*)(x + (size_t)b * kDIn);

    float acc = 0.f;
#pragma unroll
    for (int it = 0; it < 4; ++it) {
        const int idx = it * 64 + lane;
        acc += dot4(wr[idx], xr[idx]);
    }
    acc = waveReduceSum(acc);
    if (lane == 0) outv[(size_t)b * kE + e] = acc;
}

// ---------------------------------------------------------------------------
// Kernel 2: softmax over k (out[1024:2048]) and q (out[2048:3072]) per batch.
// blockIdx.x in [0, 64): b = >>1, which = &1 (0 -> kphi, 1 -> qphi).
// 256 threads, 4 elements each (float4).
// ---------------------------------------------------------------------------
__global__ __launch_bounds__(256) void k_softmax(const float* __restrict__ outv,
                                                 float* __restrict__ kphi,
                                                 float* __restrict__ qphi) {
    const int b     = blockIdx.x >> 1;
    const int which = blockIdx.x & 1;
    const float* __restrict__ src = outv + (size_t)b * kE + kDOut + which * kDIn;
    float* __restrict__ dst = (which ? qphi : kphi) + (size_t)b * kDIn;

    const int tid = threadIdx.x;
    const float4 v = ((const float4*)src)[tid];

    // block max
    float m = fmaxf(fmaxf(v.x, v.y), fmaxf(v.z, v.w));
#pragma unroll
    for (int off = 32; off; off >>= 1) m = fmaxf(m, __shfl_xor(m, off, 64));
    __shared__ float sm[4];
    if ((tid & 63) == 0) sm[tid >> 6] = m;
    __syncthreads();
    m = fmaxf(fmaxf(sm[0], sm[1]), fmaxf(sm[2], sm[3]));

    // block sum of exp
    float4 ev;
    ev.x = expf(v.x - m); ev.y = expf(v.y - m);
    ev.z = expf(v.z - m); ev.w = expf(v.w - m);
    float s = ev.x + ev.y + ev.z + ev.w;
    s = waveReduceSum(s);
    __shared__ float ss[4];
    if ((tid & 63) == 0) ss[tid >> 6] = s;
    __syncthreads();
    s = ss[0] + ss[1] + ss[2] + ss[3];
    const float inv = 1.f / s;

    float4 o;
    o.x = ev.x * inv; o.y = ev.y * inv; o.z = ev.z * inv; o.w = ev.w * inv;
    ((float4*)dst)[tid] = o;
}

// ---------------------------------------------------------------------------
// Kernel 3: for every row (b, e):
//   y_e    = w_row . x          (only stored for e < kDOut)
//   v_e    = w_row . qphi
//   vbar_e = w_row . kphi
//   coef   = sigmoid(beta_e) * (v_e - vbar_e)
//   w_out_row = w_row + coef * kphi       (w_row held in registers)
// One wave per row. w read exactly once, written exactly once.
// ---------------------------------------------------------------------------
__global__ __launch_bounds__(256) void k_update(const float* __restrict__ w,
                                                const float* __restrict__ x,
                                                const float* __restrict__ outv,
                                                const float* __restrict__ kphi,
                                                const float* __restrict__ qphi,
                                                float* __restrict__ y_out,
                                                float* __restrict__ w_out) {
    const int gw   = (blockIdx.x * 256 + threadIdx.x) >> 6;
    const int lane = threadIdx.x & 63;
    const int b = gw / kE;
    const int e = gw % kE;

    const size_t row_off = ((size_t)b * kE + e) * kDIn;
    const float4* __restrict__ wr = (const float4*)(w + row_off);
    const float4* __restrict__ xr = (const float4*)(x + (size_t)b * kDIn);
    const float4* __restrict__ kr = (const float4*)(kphi + (size_t)b * kDIn);
    const float4* __restrict__ qr = (const float4*)(qphi + (size_t)b * kDIn);

    float4 wv[4], kv[4], qv[4];
    float acc_y = 0.f, acc_v = 0.f, acc_vb = 0.f;
#pragma unroll
    for (int it = 0; it < 4; ++it) {
        const int idx = it * 64 + lane;
        wv[it] = wr[idx];
        kv[it] = kr[idx];
        qv[it] = qr[idx];
        const float4 xv = xr[idx];
        acc_y  += dot4(wv[it], xv);
        acc_v  += dot4(wv[it], qv[it]);
        acc_vb += dot4(wv[it], kv[it]);
    }
    acc_y  = waveReduceSum(acc_y);
    acc_v  = waveReduceSum(acc_v);
    acc_vb = waveReduceSum(acc_vb);

    // beta selection: [0,1024)->b1, [1024,2048)->b2, [2048,3072)->b3, rest->b4
    const int bi = (e < kDOut) ? 0 : (e < kDOut + kDIn) ? 1 : (e < kDOut + 2 * kDIn) ? 2 : 3;
    const float beta = outv[(size_t)b * kE + (kE - 4) + bi];
    const float sig  = 1.f / (1.f + expf(-beta));
    const float coef = sig * (acc_v - acc_vb);

    float4* __restrict__ orow = (float4*)(w_out + row_off);
#pragma unroll
    for (int it = 0; it < 4; ++it) {
        const int idx = it * 64 + lane;
        float4 o;
        o.x = wv[it].x + coef * kv[it].x;
        o.y = wv[it].y + coef * kv[it].y;
        o.z = wv[it].z + coef * kv[it].z;
        o.w = wv[it].w + coef * kv[it].w;
        orow[idx] = o;
    }

    if (e < kDOut && lane == 0) y_out[(size_t)b * kDOut + e] = acc_y;
}

// ---------------------------------------------------------------------------
extern "C" void kernel_launch(void* const* d_in, const int* in_sizes, int n_in,
                              void* d_out, int out_size, void* d_ws, size_t ws_size,
                              hipStream_t stream) {
    const float* x = (const float*)d_in[0];   // (32, 1024)
    const float* w = (const float*)d_in[1];   // (32, 3076, 1024)

    float* y_out = (float*)d_out;                         // 32*1024
    float* w_out = (float*)d_out + (size_t)kBatch * kDOut; // 32*3076*1024

    // workspace layout (floats)
    float* outv = (float*)d_ws;                              // 32*3076
    float* kphi = outv + (size_t)kBatch * kE;                // 32*1024
    float* qphi = kphi + (size_t)kBatch * kDIn;              // 32*1024

    // Kernel 1: 32 * 2052 rows, 4 rows (waves) per block
    {
        const int blocks = (kBatch * kKQRows) / 4;  // 16416
        k_matvec_kq<<<blocks, 256, 0, stream>>>(w, x, outv);
    }
    // Kernel 2: 32 batches x {k, q}
    k_softmax<<<kBatch * 2, 256, 0, stream>>>(outv, kphi, qphi);

    // Kernel 3: 32 * 3076 rows, 4 rows per block
    {
        const int blocks = (kBatch * kE) / 4;  // 24608
        k_update<<<blocks, 256, 0, stream>>>(w, x, outv, kphi, qphi, y_out, w_out);
    }
}